// Round 12
// baseline (42.581 us; speedup 1.0000x reference)
//
#include <hip/hip_runtime.h>
#include <hip/hip_bf16.h>

#define HW 16384
#define NB 4

typedef __attribute__((ext_vector_type(8))) short bf16x8;
typedef __attribute__((ext_vector_type(4))) float f32x4;

__device__ __forceinline__ float blo(unsigned u) { return __uint_as_float(u << 16); }
__device__ __forceinline__ float bhi(unsigned u) { return __uint_as_float(u & 0xffff0000u); }

// packed bf16 pair dot: a[0]*b[0] + a[1]*b[1] + c, f32 accumulate
__device__ __forceinline__ float bdot(unsigned k, unsigned q, float c) {
#if __has_builtin(__builtin_amdgcn_fdot2_f32_bf16)
    typedef __attribute__((ext_vector_type(2))) __bf16 bf16x2;
    return __builtin_amdgcn_fdot2_f32_bf16(__builtin_bit_cast(bf16x2, k),
                                           __builtin_bit_cast(bf16x2, q), c, false);
#else
    return fmaf(blo(k), blo(q), fmaf(bhi(k), bhi(q), c));
#endif
}

__device__ __forceinline__ int refl(int i) {
    return i < 0 ? -i : (i > 127 ? 254 - i : i);
}

// ws byte layout:
// [0,16384)      Wbf16 [2][64 d][64 c] ushort (0=keys, 1=queries*0.125)
// [16384,16896)  combined bias f32 [128] (query half pre-scaled by 0.125)
// [32768,+4.2MB) keys    bf16 [4][16384][64]
// [+4.2MB,...)   queries bf16 [4][16384][64] (pre-scaled by 0.125)

// ---------------- Kernel A: fold linear layers (R10-proven) ----------------
__global__ __launch_bounds__(256) void combine_weights(
    const float* __restrict__ conv_w, const float* __restrict__ conv_b,
    const float* __restrict__ key_w, const float* __restrict__ key_b,
    const float* __restrict__ query_w, const float* __restrict__ query_b,
    ushort* __restrict__ Wb, float* __restrict__ bout) {
    int t = threadIdx.x, bx = blockIdx.x;
    int sel = bx >> 4, d0 = (bx & 15) * 4;
    const float* Wm = sel ? query_w : key_w;
    float scale = sel ? 0.125f : 1.0f;
    int dd = t >> 6, c = t & 63;
    const float* wrow = Wm + (d0 + dd) * 64;
    float acc = 0.f;
    #pragma unroll
    for (int k = 0; k < 64; ++k) acc = fmaf(wrow[k], conv_w[k * 64 + c], acc);
    __hip_bfloat16 h = __float2bfloat16(acc * scale);
    Wb[(sel * 64 + d0 + dd) * 64 + c] = *(ushort*)&h;
    if (t < 4) {
        const float* wr2 = Wm + (d0 + t) * 64;
        float bacc = 0.f;
        #pragma unroll
        for (int k = 0; k < 64; ++k) bacc = fmaf(wr2[k], conv_b[k], bacc);
        bacc += (sel ? query_b : key_b)[d0 + t];
        bout[sel * 64 + d0 + t] = bacc * scale;
    }
}

// ---------------- Kernel B: MFMA GEMM (R10-proven) ----------------
__global__ __launch_bounds__(256) void gemm_kq(
    const float* __restrict__ x, const ushort* __restrict__ W,
    const float* __restrict__ bias, ushort* __restrict__ keys,
    ushort* __restrict__ queries) {
    __shared__ ushort xs[128 * 64];
    __shared__ ushort epi[2 * 128 * 64];
    __shared__ float bs[128];
    int t = threadIdx.x;
    int b = blockIdx.x >> 7;
    int n0 = (blockIdx.x & 127) << 7;

    if (t < 128) bs[t] = bias[t];
    {
        int c0 = (t >> 5) * 8, nb = (t & 31) * 4;
        const float* xp = x + ((size_t)(b * 64 + c0)) * HW + n0 + nb;
        float4 v[8];
        #pragma unroll
        for (int r = 0; r < 8; ++r) v[r] = *(const float4*)(xp + (size_t)r * HW);
        int chunk = c0 >> 3;
        #pragma unroll
        for (int nn = 0; nn < 4; ++nn) {
            unsigned u[4];
            #pragma unroll
            for (int cc = 0; cc < 4; ++cc) {
                float lo = ((const float*)&v[2 * cc])[nn];
                float hi = ((const float*)&v[2 * cc + 1])[nn];
                __hip_bfloat162 h2 = __float22bfloat162_rn(make_float2(lo, hi));
                u[cc] = *(unsigned*)&h2;
            }
            int row = nb + nn;
            *(uint4*)((char*)xs + row * 128 + ((chunk ^ (row & 7)) << 4)) =
                make_uint4(u[0], u[1], u[2], u[3]);
        }
    }
    __syncthreads();

    int l = t & 63, w = t >> 6;
    int ncol = l & 15, kg = l >> 4;
    int nhalf = w & 1, dhalf = w >> 1;

    bf16x8 Bf[4][2];
    #pragma unroll
    for (int nt = 0; nt < 4; ++nt) {
        int row = nhalf * 64 + nt * 16 + ncol;
        #pragma unroll
        for (int half = 0; half < 2; ++half)
            Bf[nt][half] = *(bf16x8*)((char*)xs + row * 128 + (((half * 4 + kg) ^ (row & 7)) << 4));
    }

    f32x4 acc[4][4];
    #pragma unroll
    for (int dt = 0; dt < 4; ++dt)
        #pragma unroll
        for (int nt = 0; nt < 4; ++nt) acc[dt][nt] = (f32x4){0.f, 0.f, 0.f, 0.f};

    #pragma unroll
    for (int dt = 0; dt < 4; ++dt) {
        const bf16x8* arow = (const bf16x8*)(W + ((dhalf * 64 + dt * 16 + ncol)) * 64 + kg * 8);
        bf16x8 A0 = arow[0];
        bf16x8 A1 = arow[4];
        #pragma unroll
        for (int nt = 0; nt < 4; ++nt) {
            acc[dt][nt] = __builtin_amdgcn_mfma_f32_16x16x32_bf16(A0, Bf[nt][0], acc[dt][nt], 0, 0, 0);
            acc[dt][nt] = __builtin_amdgcn_mfma_f32_16x16x32_bf16(A1, Bf[nt][1], acc[dt][nt], 0, 0, 0);
        }
    }

    #pragma unroll
    for (int dt = 0; dt < 4; ++dt) {
        int dbase = dt * 16 + kg * 4;
        float4 bb = *(float4*)&bs[dhalf * 64 + dbase];
        #pragma unroll
        for (int nt = 0; nt < 4; ++nt) {
            int nl = nhalf * 64 + nt * 16 + ncol;
            f32x4 a = acc[dt][nt];
            __hip_bfloat162 lo2 = __float22bfloat162_rn(make_float2(a[0] + bb.x, a[1] + bb.y));
            __hip_bfloat162 hi2 = __float22bfloat162_rn(make_float2(a[2] + bb.z, a[3] + bb.w));
            *(uint2*)((char*)epi + dhalf * 16384 + nl * 128 +
                      (((dbase >> 3) ^ (nl & 7)) << 4) + ((dbase & 4) << 1)) =
                make_uint2(*(unsigned*)&lo2, *(unsigned*)&hi2);
        }
    }
    __syncthreads();
    #pragma unroll
    for (int i = 0; i < 8; ++i) {
        int u = i * 256 + t;
        int arr = u >> 10;
        int row = (u >> 3) & 127, ch = u & 7;
        uint4 v = *(uint4*)((char*)epi + arr * 16384 + row * 128 + ((ch ^ (row & 7)) << 4));
        ushort* dst = arr ? queries : keys;
        *(uint4*)(dst + (((size_t)(b * HW + n0 + row)) << 6) + ch * 8) = v;
    }
}

// ---------------- Kernel C: LDS-staged halo gather + dot ----------------
// 1024 blocks; block = 64 nodes (half an image row). Halo 5x68 key rows staged
// (reflection applied at staging) -> inner loop is pure LDS reads, no reflect.

#define LSAMP(s_, dy_, dx_) do {                                              \
    int lrow = l2 + ((dy_) + 2) * 68 + (dx_);                                 \
    uint4 ka = *(const uint4*)((char*)klds + lrow * 128 +                     \
                               (((2 * j) ^ (lrow & 7)) << 4));                \
    uint4 kc = *(const uint4*)((char*)klds + lrow * 128 +                     \
                               (((2 * j + 1) ^ (lrow & 7)) << 4));            \
    float a0, a1;                                                             \
    a0 = bdot(ka.x, qa.x, 0.f);                                               \
    a0 = bdot(ka.y, qa.y, a0);                                                \
    a0 = bdot(ka.z, qa.z, a0);                                                \
    a0 = bdot(ka.w, qa.w, a0);                                                \
    a1 = bdot(kc.x, qb.x, 0.f);                                               \
    a1 = bdot(kc.y, qb.y, a1);                                                \
    a1 = bdot(kc.z, qb.z, a1);                                                \
    a1 = bdot(kc.w, qb.w, a1);                                                \
    float a = a0 + a1;                                                        \
    a += __shfl_xor(a, 1);                                                    \
    a += __shfl_xor(a, 2);                                                    \
    if (j == 0) res[l * 26 + (s_)] = a;                                       \
} while (0)

__global__ __launch_bounds__(256) void affinity(
    const ushort* __restrict__ keys, const ushort* __restrict__ queries,
    const int* __restrict__ rnd, float* __restrict__ out) {
    __shared__ ushort klds[340 * 64];   // 43.5 KB: [5 rows x 68 cols][64 d] swizzled
    __shared__ float res[64 * 26];      // 6.7 KB
    int t = threadIdx.x;
    int bid = blockIdx.x;
    int b = bid >> 8;
    int rem = bid & 255;
    int y = rem >> 1;
    int x0 = (rem & 1) << 6;
    int n0 = (y << 7) + x0;

    const ushort* kbase = keys + (((size_t)b * HW) << 6);

    // ---- stage halo: 340 rows x 8 chunks = 2720 uint4s, reflection here ----
    for (int u = t; u < 2720; u += 256) {
        int srow = u >> 3, chunk = u & 7;
        int r = srow / 68, c = srow - r * 68;
        int yy = refl(y + r - 2);
        int xx = refl(x0 + c - 2);
        uint4 v = *(const uint4*)(kbase + (((size_t)((yy << 7) + xx)) << 6) + chunk * 8);
        *(uint4*)((char*)klds + srow * 128 + ((chunk ^ (srow & 7)) << 4)) = v;
    }

    int j = t & 3;              // d slice j*16..+15
    int l = t >> 2;             // node local 0..63
    int l2 = l + 2;
    int n = n0 + l;

    const uint4* qp = (const uint4*)(queries + (((size_t)(b * HW + n)) << 6) + j * 16);
    uint4 qa = qp[0], qb = qp[1];
    int rix = rnd[b * HW + n];
    __syncthreads();

    // 25 local samples from LDS
    LSAMP(0, -2, -2);  LSAMP(1, -2, -1);  LSAMP(2, -2, 0);   LSAMP(3, -2, 1);
    LSAMP(4, -2, 2);   LSAMP(5, -1, -2);  LSAMP(6, -1, -1);  LSAMP(7, -1, 0);
    LSAMP(8, -1, 1);   LSAMP(9, -1, 2);   LSAMP(10, 0, -2);  LSAMP(11, 0, -1);
    LSAMP(12, 0, 0);   LSAMP(13, 0, 1);   LSAMP(14, 0, 2);   LSAMP(15, 1, -2);
    LSAMP(16, 1, -1);  LSAMP(17, 1, 0);   LSAMP(18, 1, 1);   LSAMP(19, 1, 2);
    LSAMP(20, 2, -2);  LSAMP(21, 2, -1);  LSAMP(22, 2, 0);   LSAMP(23, 2, 1);
    LSAMP(24, 2, 2);

    // random global sample (element slice j*16, matching the LDS path)
    {
        const uint4* kp = (const uint4*)(kbase + ((size_t)rix << 6) + j * 16);
        uint4 ka = kp[0], kc = kp[1];
        float a0, a1;
        a0 = bdot(ka.x, qa.x, 0.f);
        a0 = bdot(ka.y, qa.y, a0);
        a0 = bdot(ka.z, qa.z, a0);
        a0 = bdot(ka.w, qa.w, a0);
        a1 = bdot(kc.x, qb.x, 0.f);
        a1 = bdot(kc.y, qb.y, a1);
        a1 = bdot(kc.z, qb.z, a1);
        a1 = bdot(kc.w, qb.w, a1);
        float a = a0 + a1;
        a += __shfl_xor(a, 1);
        a += __shfl_xor(a, 2);
        if (j == 0) res[l * 26 + 25] = a;
    }

    __syncthreads();
    size_t ob = ((size_t)(b * HW + n0)) * 26;
    #pragma unroll
    for (int i = 0; i < 7; ++i) {
        int idx = i * 256 + t;
        if (idx < 1664) out[ob + idx] = res[idx];
    }
}

extern "C" void kernel_launch(void* const* d_in, const int* in_sizes, int n_in,
                              void* d_out, int out_size, void* d_ws, size_t ws_size,
                              hipStream_t stream) {
    const float* x       = (const float*)d_in[0];
    const float* conv_w  = (const float*)d_in[1];
    const float* conv_b  = (const float*)d_in[2];
    const float* key_w   = (const float*)d_in[3];
    const float* key_b   = (const float*)d_in[4];
    const float* query_w = (const float*)d_in[5];
    const float* query_b = (const float*)d_in[6];
    const int*   rnd     = (const int*)d_in[7];
    float* out = (float*)d_out;

    ushort* Wb    = (ushort*)d_ws;
    float*  biasp = (float*)((char*)d_ws + 16384);
    ushort* keys  = (ushort*)((char*)d_ws + 32768);
    ushort* quer  = keys + (size_t)NB * HW * 64;

    combine_weights<<<32, 256, 0, stream>>>(conv_w, conv_b, key_w, key_b,
                                            query_w, query_b, Wb, biasp);
    gemm_kq<<<NB * (HW / 128), 256, 0, stream>>>(x, Wb, biasp, keys, quer);
    affinity<<<NB * (HW / 16) / 4, 256, 0, stream>>>(keys, quer, rnd, out);
}

// Round 13
// 33.835 us; speedup vs baseline: 1.2585x; 1.2585x over previous
//
#include <hip/hip_runtime.h>
#include <hip/hip_bf16.h>

#define HW 16384
#define NB 4

typedef __attribute__((ext_vector_type(8))) short bf16x8;
typedef __attribute__((ext_vector_type(4))) float f32x4;

__device__ __forceinline__ float blo(unsigned u) { return __uint_as_float(u << 16); }
__device__ __forceinline__ float bhi(unsigned u) { return __uint_as_float(u & 0xffff0000u); }

// packed bf16 pair dot: a[0]*b[0] + a[1]*b[1] + c, f32 accumulate
__device__ __forceinline__ float bdot(unsigned k, unsigned q, float c) {
#if __has_builtin(__builtin_amdgcn_fdot2_f32_bf16)
    typedef __attribute__((ext_vector_type(2))) __bf16 bf16x2;
    return __builtin_amdgcn_fdot2_f32_bf16(__builtin_bit_cast(bf16x2, k),
                                           __builtin_bit_cast(bf16x2, q), c, false);
#else
    return fmaf(blo(k), blo(q), fmaf(bhi(k), bhi(q), c));
#endif
}

// ws byte layout:
// [0,16384)      Wbf16 [2][64 d][64 c] ushort (0=keys, 1=queries*0.125)
// [16384,16896)  combined bias f32 [128] (query half pre-scaled by 0.125)
// [32768,+4.2MB) keys    bf16 [4][16384][64]
// [+4.2MB,...)   queries bf16 [4][16384][64] (pre-scaled by 0.125)

// ---------------- Kernel A: fold linear layers (LDS-free) ----------------
__global__ __launch_bounds__(256) void combine_weights(
    const float* __restrict__ conv_w, const float* __restrict__ conv_b,
    const float* __restrict__ key_w, const float* __restrict__ key_b,
    const float* __restrict__ query_w, const float* __restrict__ query_b,
    ushort* __restrict__ Wb, float* __restrict__ bout) {
    int t = threadIdx.x, bx = blockIdx.x;
    int sel = bx >> 4, d0 = (bx & 15) * 4;
    const float* Wm = sel ? query_w : key_w;
    float scale = sel ? 0.125f : 1.0f;      // fold C^-0.5 into the query side (exact)
    int dd = t >> 6, c = t & 63;
    const float* wrow = Wm + (d0 + dd) * 64;   // wave-uniform
    float acc = 0.f;
    #pragma unroll
    for (int k = 0; k < 64; ++k) acc = fmaf(wrow[k], conv_w[k * 64 + c], acc);
    __hip_bfloat16 h = __float2bfloat16(acc * scale);
    Wb[(sel * 64 + d0 + dd) * 64 + c] = *(ushort*)&h;
    if (t < 4) {
        const float* wr2 = Wm + (d0 + t) * 64;
        float bacc = 0.f;
        #pragma unroll
        for (int k = 0; k < 64; ++k) bacc = fmaf(wr2[k], conv_b[k], bacc);
        bacc += (sel ? query_b : key_b)[d0 + t];
        bout[sel * 64 + d0 + t] = bacc * scale;
    }
}

// ---------------- Kernel B: MFMA GEMM, 128-node tiles, float4-along-n staging ----------------
// 512 blocks. Waves: 2n x 2d grid, each wave 64n x 64d (32 MFMA).
__global__ __launch_bounds__(256) void gemm_kq(
    const float* __restrict__ x, const ushort* __restrict__ W,
    const float* __restrict__ bias, ushort* __restrict__ keys,
    ushort* __restrict__ queries) {
    __shared__ ushort xs[128 * 64];      // 16 KB, [n][c] bf16, 16B-chunk XOR swizzle
    __shared__ ushort epi[2 * 128 * 64]; // 32 KB: [arr][n][64 d]
    __shared__ float bs[128];
    int t = threadIdx.x;
    int b = blockIdx.x >> 7;
    int n0 = (blockIdx.x & 127) << 7;

    if (t < 128) bs[t] = bias[t];
    {   // stage: thread -> c rows c0..c0+7, nodes nb..nb+3 (float4 along n)
        int c0 = (t >> 5) * 8, nb = (t & 31) * 4;
        const float* xp = x + ((size_t)(b * 64 + c0)) * HW + n0 + nb;
        float4 v[8];
        #pragma unroll
        for (int r = 0; r < 8; ++r) v[r] = *(const float4*)(xp + (size_t)r * HW);
        int chunk = c0 >> 3;
        #pragma unroll
        for (int nn = 0; nn < 4; ++nn) {
            unsigned u[4];
            #pragma unroll
            for (int cc = 0; cc < 4; ++cc) {
                float lo = ((const float*)&v[2 * cc])[nn];
                float hi = ((const float*)&v[2 * cc + 1])[nn];
                __hip_bfloat162 h2 = __float22bfloat162_rn(make_float2(lo, hi));
                u[cc] = *(unsigned*)&h2;
            }
            int row = nb + nn;
            *(uint4*)((char*)xs + row * 128 + ((chunk ^ (row & 7)) << 4)) =
                make_uint4(u[0], u[1], u[2], u[3]);
        }
    }
    __syncthreads();

    int l = t & 63, w = t >> 6;
    int ncol = l & 15, kg = l >> 4;
    int nhalf = w & 1, dhalf = w >> 1;

    bf16x8 Bf[4][2];
    #pragma unroll
    for (int nt = 0; nt < 4; ++nt) {
        int row = nhalf * 64 + nt * 16 + ncol;
        #pragma unroll
        for (int half = 0; half < 2; ++half)
            Bf[nt][half] = *(bf16x8*)((char*)xs + row * 128 + (((half * 4 + kg) ^ (row & 7)) << 4));
    }

    f32x4 acc[4][4];   // [dt][nt]
    #pragma unroll
    for (int dt = 0; dt < 4; ++dt)
        #pragma unroll
        for (int nt = 0; nt < 4; ++nt) acc[dt][nt] = (f32x4){0.f, 0.f, 0.f, 0.f};

    #pragma unroll
    for (int dt = 0; dt < 4; ++dt) {
        const bf16x8* arow = (const bf16x8*)(W + ((dhalf * 64 + dt * 16 + ncol)) * 64 + kg * 8);
        bf16x8 A0 = arow[0];
        bf16x8 A1 = arow[4];
        #pragma unroll
        for (int nt = 0; nt < 4; ++nt) {
            acc[dt][nt] = __builtin_amdgcn_mfma_f32_16x16x32_bf16(A0, Bf[nt][0], acc[dt][nt], 0, 0, 0);
            acc[dt][nt] = __builtin_amdgcn_mfma_f32_16x16x32_bf16(A1, Bf[nt][1], acc[dt][nt], 0, 0, 0);
        }
    }

    // epilogue: wave writes its 64n x 64d into epi[dhalf]
    #pragma unroll
    for (int dt = 0; dt < 4; ++dt) {
        int dbase = dt * 16 + kg * 4;
        float4 bb = *(float4*)&bs[dhalf * 64 + dbase];
        #pragma unroll
        for (int nt = 0; nt < 4; ++nt) {
            int nl = nhalf * 64 + nt * 16 + ncol;
            f32x4 a = acc[dt][nt];
            __hip_bfloat162 lo2 = __float22bfloat162_rn(make_float2(a[0] + bb.x, a[1] + bb.y));
            __hip_bfloat162 hi2 = __float22bfloat162_rn(make_float2(a[2] + bb.z, a[3] + bb.w));
            *(uint2*)((char*)epi + dhalf * 16384 + nl * 128 +
                      (((dbase >> 3) ^ (nl & 7)) << 4) + ((dbase & 4) << 1)) =
                make_uint2(*(unsigned*)&lo2, *(unsigned*)&hi2);
        }
    }
    __syncthreads();
    #pragma unroll
    for (int i = 0; i < 8; ++i) {
        int u = i * 256 + t;              // 0..2047 uint4s
        int arr = u >> 10;                // 0=keys, 1=queries
        int row = (u >> 3) & 127, ch = u & 7;
        uint4 v = *(uint4*)((char*)epi + arr * 16384 + row * 128 + ((ch ^ (row & 7)) << 4));
        ushort* dst = arr ? queries : keys;
        *(uint4*)(dst + (((size_t)(b * HW + n0 + row)) << 6) + ch * 8) = v;
    }
}

// ---------------- Kernel C: gather + dot via v_dot2_f32_bf16 ----------------
#define DOT(s_, idxn_) do {                                                   \
    const uint4* kp = (const uint4*)(kb_ + ((size_t)(idxn_) << 6));           \
    uint4 ka = kp[0], kc = kp[1];                                             \
    float a0, a1;                                                             \
    a0 = bdot(ka.x, qa.x, 0.f);                                               \
    a0 = bdot(ka.y, qa.y, a0);                                                \
    a0 = bdot(ka.z, qa.z, a0);                                                \
    a0 = bdot(ka.w, qa.w, a0);                                                \
    a1 = bdot(kc.x, qb.x, 0.f);                                               \
    a1 = bdot(kc.y, qb.y, a1);                                                \
    a1 = bdot(kc.z, qb.z, a1);                                                \
    a1 = bdot(kc.w, qb.w, a1);                                                \
    float a = a0 + a1;                                                        \
    a += __shfl_xor(a, 1);                                                    \
    a += __shfl_xor(a, 2);                                                    \
    if (j == 0) res[n_loc * 26 + (s_)] = a;                                   \
} while (0)

#define SAMP(s_, dy_, dx_) do {                                               \
    int ry = y + (dy_);                                                       \
    if ((dy_) < 0) ry = (ry < 0) ? -ry : ry;                                  \
    if ((dy_) > 0) ry = (ry > 127) ? 254 - ry : ry;                           \
    int rx = xq + (dx_);                                                      \
    if ((dx_) < 0) rx = (rx < 0) ? -rx : rx;                                  \
    if ((dx_) > 0) rx = (rx > 127) ? 254 - rx : rx;                           \
    DOT(s_, (ry << 7) + rx);                                                  \
} while (0)

__global__ __launch_bounds__(256) void affinity(
    const ushort* __restrict__ keys, const ushort* __restrict__ queries,
    const int* __restrict__ rnd, float* __restrict__ out) {
    __shared__ float res[416];
    int t = threadIdx.x;
    int b = blockIdx.x >> 10;
    int n0 = (blockIdx.x & 1023) << 4;

    int j = t & 3;
    int g = t >> 2;
    int n_loc = g & 15;
    int sb = g >> 4;          // wave-uniform sample phase
    int n = n0 + n_loc;

    const uint4* qp = (const uint4*)(queries + (((size_t)(b * HW + n)) << 6) + j * 16);
    uint4 qa = qp[0], qb = qp[1];

    int y = n >> 7, xq = n & 127;
    const ushort* kb_ = keys + (((size_t)b * HW) << 6) + j * 16;

    switch (sb) {
    case 0:
        SAMP(0, -2, -2); SAMP(4, -2, 2);  SAMP(8, -1, 1);  SAMP(12, 0, 0);
        SAMP(16, 1, -1); SAMP(20, 2, -2); SAMP(24, 2, 2);
        break;
    case 1: {
        SAMP(1, -2, -1); SAMP(5, -1, -2); SAMP(9, -1, 2);  SAMP(13, 0, 1);
        SAMP(17, 1, 0);  SAMP(21, 2, -1);
        int rix = rnd[b * HW + n];
        DOT(25, rix);
        break;
    }
    case 2:
        SAMP(2, -2, 0);  SAMP(6, -1, -1); SAMP(10, 0, -2); SAMP(14, 0, 2);
        SAMP(18, 1, 1);  SAMP(22, 2, 0);
        break;
    default:
        SAMP(3, -2, 1);  SAMP(7, -1, 0);  SAMP(11, 0, -1); SAMP(15, 1, -2);
        SAMP(19, 1, 2);  SAMP(23, 2, 1);
        break;
    }
    __syncthreads();
    size_t ob = ((size_t)(b * HW + n0)) * 26;
    out[ob + t] = res[t];
    if (t < 160) out[ob + 256 + t] = res[256 + t];
}

extern "C" void kernel_launch(void* const* d_in, const int* in_sizes, int n_in,
                              void* d_out, int out_size, void* d_ws, size_t ws_size,
                              hipStream_t stream) {
    const float* x       = (const float*)d_in[0];
    const float* conv_w  = (const float*)d_in[1];
    const float* conv_b  = (const float*)d_in[2];
    const float* key_w   = (const float*)d_in[3];
    const float* key_b   = (const float*)d_in[4];
    const float* query_w = (const float*)d_in[5];
    const float* query_b = (const float*)d_in[6];
    const int*   rnd     = (const int*)d_in[7];
    float* out = (float*)d_out;

    ushort* Wb    = (ushort*)d_ws;
    float*  biasp = (float*)((char*)d_ws + 16384);
    ushort* keys  = (ushort*)((char*)d_ws + 32768);
    ushort* quer  = keys + (size_t)NB * HW * 64;

    combine_weights<<<32, 256, 0, stream>>>(conv_w, conv_b, key_w, key_b,
                                            query_w, query_b, Wb, biasp);
    gemm_kq<<<NB * (HW / 128), 256, 0, stream>>>(x, Wb, biasp, keys, quer);
    affinity<<<NB * (HW / 16), 256, 0, stream>>>(keys, quer, rnd, out);
}